// Round 1
// baseline (60.855 us; speedup 1.0000x reference)
//
#include <hip/hip_runtime.h>
#include <hip/hip_bf16.h>

// Problem constants (from reference)
constexpr int ROWS = 4096;
constexpr int COLS = 11008;
constexpr int CODEBOOK_NUM = 2;
constexpr int CENTROIDS_NUM = 256;
constexpr int VEC_DIM = 4;
constexpr long long N_VECS = (long long)ROWS * COLS / VEC_DIM;   // 11,272,192
constexpr long long HALF_VECS = N_VECS / CODEBOOK_NUM;           // 5,636,096 (divisible by 4)
constexpr long long N_GROUPS = N_VECS / 4;                        // 2,818,048 (= 11008 * 256)

// Each thread handles 4 consecutive vectors (16 output floats = one float4 x4).
// codes:      [2, N_VECS/2] int32, flattened row-major -> first half uses codebook 0
// codebooks:  [2, 256, 4] f32 -> 512 float4 rows
// scales:     [N_BLOCKS, 1] f32, block = 64 elements = 16 vectors -> scale idx = g/4
__global__ __launch_bounds__(256) void dequant_kernel(
    const int* __restrict__ codes,
    const float* __restrict__ codebooks,
    const float* __restrict__ scales,
    float* __restrict__ out)
{
    __shared__ float4 cb[CODEBOOK_NUM * CENTROIDS_NUM];  // 512 x 16B = 8 KB

    const int tid = threadIdx.x;
    // Cooperative codebook stage: 512 float4 / 256 threads = 2 each
    const float4* cb_g = reinterpret_cast<const float4*>(codebooks);
    cb[tid] = cb_g[tid];
    cb[tid + 256] = cb_g[tid + 256];
    __syncthreads();

    long long g = (long long)blockIdx.x * 256 + tid;     // group index
    if (g >= N_GROUPS) return;

    const int4 c = reinterpret_cast<const int4*>(codes)[g];
    const float s = scales[g >> 2];

    // All 4 vectors of a group lie in the same codebook half (HALF_VECS % 4 == 0)
    const int off = ((g * 4) < HALF_VECS) ? 0 : CENTROIDS_NUM;

    float4 v0 = cb[c.x + off];
    float4 v1 = cb[c.y + off];
    float4 v2 = cb[c.z + off];
    float4 v3 = cb[c.w + off];

    v0.x *= s; v0.y *= s; v0.z *= s; v0.w *= s;
    v1.x *= s; v1.y *= s; v1.z *= s; v1.w *= s;
    v2.x *= s; v2.y *= s; v2.z *= s; v2.w *= s;
    v3.x *= s; v3.y *= s; v3.z *= s; v3.w *= s;

    float4* out4 = reinterpret_cast<float4*>(out);
    const long long base = g * 4;
    out4[base + 0] = v0;
    out4[base + 1] = v1;
    out4[base + 2] = v2;
    out4[base + 3] = v3;
}

extern "C" void kernel_launch(void* const* d_in, const int* in_sizes, int n_in,
                              void* d_out, int out_size, void* d_ws, size_t ws_size,
                              hipStream_t stream) {
    const int*   codes     = (const int*)d_in[0];
    const float* codebooks = (const float*)d_in[1];
    const float* scales    = (const float*)d_in[2];
    float*       out       = (float*)d_out;

    const int block = 256;
    const long long grid = (N_GROUPS + block - 1) / block;   // 11008 exactly
    dequant_kernel<<<(int)grid, block, 0, stream>>>(codes, codebooks, scales, out);
}

// Round 2
// 43.440 us; speedup vs baseline: 1.4009x; 1.4009x over previous
//
#include <hip/hip_runtime.h>
#include <hip/hip_bf16.h>

// Problem constants (from reference)
constexpr int ROWS = 4096;
constexpr int COLS = 11008;
constexpr int CODEBOOK_NUM = 2;
constexpr int CENTROIDS_NUM = 256;
constexpr int VEC_DIM = 4;
constexpr long long N_VECS = (long long)ROWS * COLS / VEC_DIM;   // 11,272,192
constexpr long long HALF_VECS = N_VECS / CODEBOOK_NUM;           // 5,636,096 = 5504 * 1024

typedef float f32x4 __attribute__((ext_vector_type(4)));

// Block = 256 threads; each block covers 1024 consecutive vectors.
// Thread (wave w, lane l) handles vectors vbase + {0,64,128,192} where
// vbase = blk*1024 + w*256 + l  -> every load/store instruction in a wave
// touches a fully contiguous range:
//   codes:  64 lanes x 4 B   = 256 B contiguous per instruction
//   out:    64 lanes x 16 B  = 1 KB contiguous per instruction
// HALF_VECS % 1024 == 0 -> codebook-half offset is block-uniform.
__global__ __launch_bounds__(256) void dequant_kernel(
    const int* __restrict__ codes,
    const float* __restrict__ codebooks,
    const float* __restrict__ scales,
    f32x4* __restrict__ out4)
{
    __shared__ f32x4 cb[CODEBOOK_NUM * CENTROIDS_NUM];  // 8 KB

    const int tid = threadIdx.x;
    const f32x4* cb_g = reinterpret_cast<const f32x4*>(codebooks);
    cb[tid]       = cb_g[tid];
    cb[tid + 256] = cb_g[tid + 256];
    __syncthreads();

    const int lane = tid & 63;
    const int wave = tid >> 6;
    const long long vbase = (long long)blockIdx.x * 1024 + wave * 256 + lane;
    const int off = (vbase < HALF_VECS) ? 0 : CENTROIDS_NUM;   // block-uniform

    // Issue all global reads first (memory-level parallelism: 8 loads in flight)
    int   c[4];
    float s[4];
#pragma unroll
    for (int k = 0; k < 4; ++k) {
        const long long v = vbase + (long long)k * 64;
        c[k] = __builtin_nontemporal_load(&codes[v]);
        s[k] = scales[v >> 4];
    }

#pragma unroll
    for (int k = 0; k < 4; ++k) {
        const long long v = vbase + (long long)k * 64;
        f32x4 e = cb[c[k] + off];
        e *= s[k];
        __builtin_nontemporal_store(e, &out4[v]);
    }
}

extern "C" void kernel_launch(void* const* d_in, const int* in_sizes, int n_in,
                              void* d_out, int out_size, void* d_ws, size_t ws_size,
                              hipStream_t stream) {
    const int*   codes     = (const int*)d_in[0];
    const float* codebooks = (const float*)d_in[1];
    const float* scales    = (const float*)d_in[2];
    f32x4*       out4      = (f32x4*)d_out;

    const int block = 256;
    const int grid = (int)(N_VECS / 1024);   // 11008, exact
    dequant_kernel<<<grid, block, 0, stream>>>(codes, codebooks, scales, out4);
}

// Round 3
// 40.195 us; speedup vs baseline: 1.5140x; 1.0807x over previous
//
#include <hip/hip_runtime.h>
#include <hip/hip_bf16.h>

// Problem constants (from reference)
constexpr int ROWS = 4096;
constexpr int COLS = 11008;
constexpr int CODEBOOK_NUM = 2;
constexpr int CENTROIDS_NUM = 256;
constexpr int VEC_DIM = 4;
constexpr long long N_VECS = (long long)ROWS * COLS / VEC_DIM;   // 11,272,192
constexpr long long HALF_VECS = N_VECS / CODEBOOK_NUM;           // 5,636,096 = 2752 * 2048

typedef float f32x4 __attribute__((ext_vector_type(4)));

// Block = 256 threads; each block covers 2048 consecutive vectors.
// Thread (wave w, lane l) handles vectors vbase + k*64, k=0..7, where
// vbase = blk*2048 + w*512 + l  -> every load/store instruction in a wave
// touches a fully contiguous range:
//   codes:  64 lanes x 4 B   = 256 B contiguous per instruction (NT: stream once)
//   out:    64 lanes x 16 B  = 1 KB contiguous per instruction (plain store, L2 WC)
// HALF_VECS % 2048 == 0 -> codebook-half offset is block-uniform.
__global__ __launch_bounds__(256) void dequant_kernel(
    const int* __restrict__ codes,
    const float* __restrict__ codebooks,
    const float* __restrict__ scales,
    f32x4* __restrict__ out4)
{
    __shared__ f32x4 cb[CODEBOOK_NUM * CENTROIDS_NUM];  // 8 KB

    const int tid = threadIdx.x;
    const f32x4* cb_g = reinterpret_cast<const f32x4*>(codebooks);
    cb[tid]       = cb_g[tid];
    cb[tid + 256] = cb_g[tid + 256];
    __syncthreads();

    const int lane = tid & 63;
    const int wave = tid >> 6;
    // wave w owns a contiguous 512-vector span within the block's 2048
    const long long vbase = (long long)blockIdx.x * 2048 + wave * 512 + lane;
    const int off = (vbase < HALF_VECS) ? 0 : CENTROIDS_NUM;   // block-uniform

    // Issue all global reads first (memory-level parallelism: 16 loads in flight)
    int   c[8];
    float s[8];
#pragma unroll
    for (int k = 0; k < 8; ++k) {
        const long long v = vbase + (long long)k * 64;
        c[k] = __builtin_nontemporal_load(&codes[v]);
        s[k] = scales[v >> 4];
    }

#pragma unroll
    for (int k = 0; k < 8; ++k) {
        const long long v = vbase + (long long)k * 64;
        f32x4 e = cb[c[k] + off];
        e *= s[k];
        out4[v] = e;   // plain store: full-line write-combining through L2
    }
}

extern "C" void kernel_launch(void* const* d_in, const int* in_sizes, int n_in,
                              void* d_out, int out_size, void* d_ws, size_t ws_size,
                              hipStream_t stream) {
    const int*   codes     = (const int*)d_in[0];
    const float* codebooks = (const float*)d_in[1];
    const float* scales    = (const float*)d_in[2];
    f32x4*       out4      = (f32x4*)d_out;

    const int block = 256;
    const int grid = (int)(N_VECS / 2048);   // 5504, exact
    dequant_kernel<<<grid, block, 0, stream>>>(codes, codebooks, scales, out4);
}